// Round 15
// baseline (462.353 us; speedup 1.0000x reference)
//
#include <hip/hip_runtime.h>

#define NN     50000
#define NE     200000
#define ETOT   250000   // NE + NN self-loops
#define FIN    165
#define KP1    192      // FIN padded to mult of 32
#define HEADS  8
#define CH     100
#define DIM    800      // 8*100
#define MPAD   50048    // 391*128
#define NP1    896      // 7*128  (pad of 816: 800 data + 16 es/ed)
#define DIM2   1600     // W2|Wres1 fused output
#define NP2    1664     // 13*128 (pad of 1616: 1600 data + 16 es/ed)
#define NEG    0.2f
#define CHK    64       // agg softmax chunk (LDS ex buffer = CHK*8 floats)

typedef unsigned short u16;
typedef unsigned int   u32;
typedef __bf16 bf16x8 __attribute__((ext_vector_type(8)));
typedef float  f32x4  __attribute__((ext_vector_type(4)));

__device__ __forceinline__ u16 f2b(float f) {
  u32 u = __float_as_uint(f);
  u = (u + 0x7FFFu + ((u >> 16) & 1u)) >> 16;   // RNE
  return (u16)u;
}
__device__ __forceinline__ float b2f(u16 u) { return __uint_as_float(((u32)u) << 16); }

// ---------------- CSR build (dst -> list of src), reused by all 3 layers ----------------
__global__ void k_count(const int* __restrict__ ei, int* __restrict__ cnt) {
  int e = blockIdx.x * 256 + threadIdx.x;
  if (e >= ETOT) return;
  int d = (e < NE) ? ei[NE + e] : (e - NE);
  atomicAdd(&cnt[d], 1);
}
__global__ void k_bsum(const int* __restrict__ cnt, int* __restrict__ bs) {
  __shared__ int sm[256];
  int i = blockIdx.x * 256 + threadIdx.x;
  sm[threadIdx.x] = (i < NN) ? cnt[i] : 0;
  __syncthreads();
  for (int off = 128; off; off >>= 1) {
    if (threadIdx.x < off) sm[threadIdx.x] += sm[threadIdx.x + off];
    __syncthreads();
  }
  if (!threadIdx.x) bs[blockIdx.x] = sm[0];
}
__global__ void k_top(int* __restrict__ bs, int* __restrict__ rs, int nb) {
  __shared__ int sm[256];
  int t = threadIdx.x;
  int v = (t < nb) ? bs[t] : 0;
  sm[t] = v; __syncthreads();
  for (int off = 1; off < 256; off <<= 1) {
    int add = (t >= off) ? sm[t - off] : 0;
    __syncthreads();
    sm[t] += add;
    __syncthreads();
  }
  if (t < nb) bs[t] = sm[t] - v;   // exclusive block offsets
  if (!t) rs[NN] = ETOT;
}
__global__ void k_scan(const int* __restrict__ cnt, const int* __restrict__ bs, int* __restrict__ rs) {
  __shared__ int sm[256];
  int t = threadIdx.x, i = blockIdx.x * 256 + t;
  int v = (i < NN) ? cnt[i] : 0;
  sm[t] = v; __syncthreads();
  for (int off = 1; off < 256; off <<= 1) {
    int add = (t >= off) ? sm[t - off] : 0;
    __syncthreads();
    sm[t] += add;
    __syncthreads();
  }
  if (i < NN) rs[i] = bs[blockIdx.x] + sm[t] - v;
}
__global__ void k_fill(const int* __restrict__ ei, const int* __restrict__ rs,
                       int* __restrict__ cur, int* __restrict__ esrc) {
  int e = blockIdx.x * 256 + threadIdx.x;
  if (e >= ETOT) return;
  int s, d;
  if (e < NE) { s = ei[e]; d = ei[NE + e]; } else { s = d = e - NE; }
  int pos = atomicAdd(&cur[d], 1);
  esrc[rs[d] + pos] = s;
}

// ==== fused prep: converts + fused-attention weight cols + x@Wskip + zero cnt/cur ====
#define PR_X   9384    // MPAD*KP1/4/256
#define PR_W1  10056   // + NP1*KP1/256 (672)
#define PR_WA1 10068   // + 16*KP1/256 (12)
#define PR_W2  15268   // + NP2*DIM/256 (5200)
#define PR_WA2 15318   // + 16*DIM/256 (50)
#define PR_L3X 27818   // + (NN+3)/4 (12500)
#define PR_Z   28209   // + ceil(2*NN/256) (391)

__device__ __forceinline__ void d_wa(int idx, const float* W, const float* as,
                                     const float* ad, u16* Wt, int Kin, int Kpad, int Dsp) {
  int j = idx / Kpad, k = idx - j * Kpad;
  int h = j & 7;
  const float* a = ((j < 8) ? as : ad) + h * CH;
  float s = 0.f;
  if (k < Kin) {
    const float* wr = W + (size_t)k * DIM + h * CH;
    for (int c = 0; c < CH; ++c) s += wr[c] * a[c];
  }
  Wt[(size_t)(Dsp + j) * Kpad + k] = f2b(s);
}

__global__ __launch_bounds__(256) void k_prep(const float* __restrict__ x,
    const float* __restrict__ W1, const float* __restrict__ a1s, const float* __restrict__ a1d,
    const float* __restrict__ W2, const float* __restrict__ Wr1,
    const float* __restrict__ a2s, const float* __restrict__ a2d,
    const float* __restrict__ Wsk,
    u16* __restrict__ A1, u16* __restrict__ W1t, u16* __restrict__ W2t,
    float* __restrict__ skp, int* __restrict__ cnt, int* __restrict__ cur) {
  int b = blockIdx.x, t = threadIdx.x;
  if (b < PR_X) {                      // x -> bf16 padded [MPAD][KP1], 4 elems/thread
    int idx4 = b * 256 + t;
    int r = idx4 / 48;                 // KP1/4 = 48
    int kq = (idx4 - r * 48) * 4;
    ushort4 o = (ushort4){0, 0, 0, 0};
    if (r < NN) {
      const float* xr = x + (size_t)r * FIN;
      float v0 = (kq + 0 < FIN) ? xr[kq + 0] : 0.f;
      float v1 = (kq + 1 < FIN) ? xr[kq + 1] : 0.f;
      float v2 = (kq + 2 < FIN) ? xr[kq + 2] : 0.f;
      float v3 = (kq + 3 < FIN) ? xr[kq + 3] : 0.f;
      o.x = f2b(v0); o.y = f2b(v1); o.z = f2b(v2); o.w = f2b(v3);
    }
    *(ushort4*)(A1 + (size_t)r * KP1 + kq) = o;
  } else if (b < PR_W1) {              // W1^T bf16 [NP1][KP1] (zero pad rows)
    int idx = (b - PR_X) * 256 + t;
    int j = idx / KP1, k = idx - j * KP1;
    float v = (j < DIM && k < FIN) ? W1[k * DIM + j] : 0.f;
    W1t[idx] = f2b(v);
  } else if (b < PR_WA1) {             // fused es/ed cols for layer 1
    int idx = (b - PR_W1) * 256 + t;
    d_wa(idx, W1, a1s, a1d, W1t, FIN, KP1, DIM);
  } else if (b < PR_W2) {              // [W2|Wres1]^T bf16 [NP2][DIM]
    int idx = (b - PR_WA1) * 256 + t;
    int j = idx / DIM, k = idx - j * DIM;
    float v = 0.f;
    if (j < DIM) v = W2[k * DIM + j];
    else if (j < 2 * DIM) v = Wr1[k * DIM + (j - DIM)];
    W2t[idx] = f2b(v);
  } else if (b < PR_WA2) {             // fused es/ed cols for layer 2
    int idx = (b - PR_W2) * 256 + t;
    d_wa(idx, W2, a2s, a2d, W2t, DIM, DIM, DIM2);
  } else if (b < PR_L3X) {             // x @ Wskip (one wave per node)
    int wv = t >> 6, lane = t & 63;
    int n = (b - PR_WA2) * 4 + wv;
    if (n >= NN) return;
    float s0 = 0.f, s1 = 0.f;
    const float* xr = x + (size_t)n * FIN;
    for (int c = lane; c < FIN; c += 64) {
      float v = xr[c];
      s0 += v * Wsk[2 * c]; s1 += v * Wsk[2 * c + 1];
    }
#pragma unroll
    for (int off = 32; off; off >>= 1) {
      s0 += __shfl_down(s0, off); s1 += __shfl_down(s1, off);
    }
    if (!lane) { skp[2 * n] = s0; skp[2 * n + 1] = s1; }
  } else {                             // zero cnt + cur
    int i = (b - PR_L3X) * 256 + t;
    if (i < NN) cnt[i] = 0;
    else if (i < 2 * NN) cur[i - NN] = 0;
  }
}

// ---------------- bf16 MFMA GEMM: 128^2 tile, BK=32, 2-phase dbuf, 8 waves ----------------
// LDS layout (R12-proven, 0 bank conflicts): 8 subtiles of [16 rows][32 k];
// within a subtile, k-block stored at col = k ^ ((row_in>>3)&1)*16.
// gload_lds dest LINEAR; GLOBAL source inverse-permuted; ds_read same XOR.
// R15: 512 threads / 8 waves, wave owns 64x32 of C -> acc[4][2] = 32 regs/wave
// (half of R14) -> ~80 total regs/wave -> 3 blocks/CU x 8 = 24 waves/CU (75% cap
// vs 50%). Each acc touched once per K-step (no dependent MFMA pairs).
__device__ __forceinline__ void gl_lds16(const u16* g, u16* l) {
  __builtin_amdgcn_global_load_lds((const __attribute__((address_space(1))) void*)g,
                                   (__attribute__((address_space(3))) void*)l, 16, 0, 0);
}

__global__ __launch_bounds__(512, 6) void k_gemm(const u16* __restrict__ A, const u16* __restrict__ Bt,
                                              u16* __restrict__ C, float* __restrict__ es,
                                              float* __restrict__ ed, int ksteps, int K,
                                              int Dsplit, int Nreal, int ldC) {
  __shared__ __align__(16) u16 lA[2][128 * 32];
  __shared__ __align__(16) u16 lB[2][128 * 32];
  int t = threadIdx.x;
  int lane = t & 63, w = t >> 6;

  // T1 XCD swizzle (bijective chunked, m204)
  int nwg = gridDim.x * gridDim.y;
  int h = blockIdx.y * gridDim.x + blockIdx.x;
  int q = nwg >> 3, r8 = nwg & 7;
  int xcd = h & 7, i8 = h >> 3;
  int ln = (xcd < r8 ? xcd * (q + 1) : r8 * (q + 1) + (xcd - r8) * q) + i8;
  int tn = (ln % gridDim.x) * 128, tm = (ln / gridDim.x) * 128;

  int wr = (w >> 2) * 64, wc = (w & 3) * 32;   // wave's 64x32 C sub-tile
  int rl = lane & 15, kl = (lane >> 4) * 8;
  int rdo = rl * 32 + (kl ^ (((rl >> 3) & 1) << 4));   // subtile-relative read offset

  f32x4 acc[4][2];
#pragma unroll
  for (int i = 0; i < 4; ++i)
#pragma unroll
    for (int j = 0; j < 2; ++j) acc[i][j] = (f32x4){0.f, 0.f, 0.f, 0.f};

  // staging: 512 threads x (1 A-chunk + 1 B-chunk) of 16B = 128x32 tile each
  int srow = ((t >> 6) << 4) + ((t >> 2) & 15);          // subtile*16 + row_in
  int skb  = ((t & 3) << 3) ^ (((t >> 5) & 1) << 4);     // inverse XOR on source
  auto stage = [&](int buf, int ks) {
    int k0 = ks * 32;
    gl_lds16(A + (size_t)(tm + srow) * K + k0 + skb, &lA[buf][t * 8]);
    gl_lds16(Bt + (size_t)(tn + srow) * K + k0 + skb, &lB[buf][t * 8]);
  };

  stage(0, 0);
  int cur = 0;
  for (int ks = 0; ks < ksteps; ++ks) {
    __syncthreads();                       // drains vmcnt(0): buf[cur] fully written
    if (ks + 1 < ksteps) stage(cur ^ 1, ks + 1);   // loads fly under the MFMAs below
    bf16x8 af[4], bfr[2];
#pragma unroll
    for (int i = 0; i < 4; ++i)
      af[i] = *(const bf16x8*)&lA[cur][(((wr + i * 16) >> 4) << 9) + rdo];
#pragma unroll
    for (int j = 0; j < 2; ++j)
      bfr[j] = *(const bf16x8*)&lB[cur][(((wc + j * 16) >> 4) << 9) + rdo];
#pragma unroll
    for (int i = 0; i < 4; ++i)
#pragma unroll
      for (int j = 0; j < 2; ++j)
        acc[i][j] = __builtin_amdgcn_mfma_f32_16x16x32_bf16(af[i], bfr[j], acc[i][j], 0, 0, 0);
    cur ^= 1;
  }
  int rq = (lane >> 4) * 4;
#pragma unroll
  for (int i = 0; i < 4; ++i) {
#pragma unroll
    for (int j = 0; j < 2; ++j) {
      int col = tn + wc + j * 16 + rl;
      if (col < Dsplit) {
#pragma unroll
        for (int q2 = 0; q2 < 4; ++q2) {
          int row = tm + wr + i * 16 + rq + q2;
          C[(size_t)row * ldC + col] = f2b(acc[i][j][q2]);
        }
      } else if (col < Nreal) {
        int cj = col - Dsplit;
        float* dst = (cj < 8) ? es : ed;
        int hh = cj & 7;
#pragma unroll
        for (int q2 = 0; q2 < 4; ++q2) {
          int row = tm + wr + i * 16 + rq + q2;
          dst[(size_t)row * 8 + hh] = acc[i][j][q2];
        }
      }
    }
  }
}

// ==== fused softmax-stats + aggregation (chunked in-LDS, no atomics) ====
// Trailing WAR-barrier skipped on the LAST chunk (avg degree 5 -> ~1 chunk/block).

// ---- layer-1: writes h1 (GEMM2 A-matrix) ----
__global__ __launch_bounds__(256) void k_agg1(const int* __restrict__ rs, const int* __restrict__ esrc,
    const u16* __restrict__ Hp, const float* __restrict__ es, const float* __restrict__ ed,
    const float* __restrict__ bias, u16* __restrict__ out) {
  __shared__ float sm_ex[CHK * 8];
  __shared__ int   sm_src[CHK];
  int n = blockIdx.x, t = threadIdx.x;
  int beg = rs[n], end = rs[n + 1];
  int c = t * 4;
  int h = t / 25;
  float edvh = ed[n * 8 + (t & 7)];    // hh for ex-production: i&7 == t&7 (256%8==0)
  float a0 = 0.f, a1 = 0.f, a2 = 0.f, a3 = 0.f, den = 0.f;
  for (int ch = beg; ch < end; ch += CHK) {
    int m = min(end, ch + CHK) - ch;
    if (t < m) sm_src[t] = esrc[ch + t];
    for (int i = t; i < m * 8; i += 256) {
      float xv = es[esrc[ch + (i >> 3)] * 8 + (i & 7)] + edvh;
      xv = xv > 0.f ? xv : NEG * xv;
      sm_ex[i] = __expf(xv);
    }
    __syncthreads();                   // publishes sm_ex + sm_src
    if (t < 200) {
      for (int j = 0; j < m; ++j) {
        float w = sm_ex[j * 8 + h];
        den += w;
        ushort4 u = *(const ushort4*)(Hp + (size_t)sm_src[j] * DIM + c);
        a0 += w * b2f(u.x); a1 += w * b2f(u.y); a2 += w * b2f(u.z); a3 += w * b2f(u.w);
      }
    }
    if (ch + CHK < end) __syncthreads();   // WAR only if another chunk follows
  }
  if (t >= 200) return;
  float inv = 1.f / (den + 1e-16f);
  const float4 bb = *(const float4*)(bias + c);
  float v0 = a0 * inv + bb.x, v1 = a1 * inv + bb.y, v2 = a2 * inv + bb.z, v3 = a3 * inv + bb.w;
  v0 = v0 > 0.f ? v0 : __expf(v0) - 1.f;
  v1 = v1 > 0.f ? v1 : __expf(v1) - 1.f;
  v2 = v2 > 0.f ? v2 : __expf(v2) - 1.f;
  v3 = v3 > 0.f ? v3 : __expf(v3) - 1.f;
  ushort4 o;
  o.x = f2b(v0); o.y = f2b(v1); o.z = f2b(v2); o.w = f2b(v3);
  *(ushort4*)(out + (size_t)n * DIM + c) = o;
}

// ---- layer-2: fused stats + agg + resid + ELU + layer-3 skinny projections ----
__global__ __launch_bounds__(256) void k_agg2f(const int* __restrict__ rs, const int* __restrict__ esrc,
    const u16* __restrict__ Hp, const float* __restrict__ es, const float* __restrict__ ed,
    const float* __restrict__ bias, const u16* __restrict__ resid,
    const float* __restrict__ W3, const float* __restrict__ Wres2,
    const float* __restrict__ a3s, const float* __restrict__ a3d, const float* __restrict__ b3,
    const float* __restrict__ skp,
    float* __restrict__ H3p, float* __restrict__ base,
    float* __restrict__ es3, float* __restrict__ ed3) {
  __shared__ float sm_ex[CHK * 8];
  __shared__ int   sm_src[CHK];
  __shared__ float red[4][4];
  int n = blockIdx.x, t = threadIdx.x;
  int lane = t & 63, wv = t >> 6;
  int beg = rs[n], end = rs[n + 1];
  int c = t * 4;
  int h = t / 25;
  float edvh = ed[n * 8 + (t & 7)];
  float a0 = 0.f, a1 = 0.f, a2 = 0.f, a3 = 0.f, den = 0.f;
  for (int ch = beg; ch < end; ch += CHK) {
    int m = min(end, ch + CHK) - ch;
    if (t < m) sm_src[t] = esrc[ch + t];
    for (int i = t; i < m * 8; i += 256) {
      float xv = es[esrc[ch + (i >> 3)] * 8 + (i & 7)] + edvh;
      xv = xv > 0.f ? xv : NEG * xv;
      sm_ex[i] = __expf(xv);
    }
    __syncthreads();
    if (t < 200) {
      for (int j = 0; j < m; ++j) {
        float w = sm_ex[j * 8 + h];
        den += w;
        ushort4 u = *(const ushort4*)(Hp + (size_t)sm_src[j] * DIM2 + c);
        a0 += w * b2f(u.x); a1 += w * b2f(u.y); a2 += w * b2f(u.z); a3 += w * b2f(u.w);
      }
    }
    if (ch + CHK < end) __syncthreads();
  }
  float p0 = 0.f, p1 = 0.f, r0 = 0.f, r1 = 0.f;
  if (t < 200) {
    float inv = 1.f / (den + 1e-16f);
    const float4 bb = *(const float4*)(bias + c);
    ushort4 rr = *(const ushort4*)(resid + (size_t)n * DIM2 + c);
    float v0 = a0 * inv + bb.x + b2f(rr.x);
    float v1 = a1 * inv + bb.y + b2f(rr.y);
    float v2 = a2 * inv + bb.z + b2f(rr.z);
    float v3 = a3 * inv + bb.w + b2f(rr.w);
    v0 = v0 > 0.f ? v0 : __expf(v0) - 1.f;
    v1 = v1 > 0.f ? v1 : __expf(v1) - 1.f;
    v2 = v2 > 0.f ? v2 : __expf(v2) - 1.f;
    v3 = v3 > 0.f ? v3 : __expf(v3) - 1.f;
    const float4 w3a = *(const float4*)(W3 + 2 * c);
    const float4 w3b = *(const float4*)(W3 + 2 * c + 4);
    const float4 wra = *(const float4*)(Wres2 + 2 * c);
    const float4 wrb = *(const float4*)(Wres2 + 2 * c + 4);
    p0 = v0 * w3a.x + v1 * w3a.z + v2 * w3b.x + v3 * w3b.z;
    p1 = v0 * w3a.y + v1 * w3a.w + v2 * w3b.y + v3 * w3b.w;
    r0 = v0 * wra.x + v1 * wra.z + v2 * wrb.x + v3 * wrb.z;
    r1 = v0 * wra.y + v1 * wra.w + v2 * wrb.y + v3 * wrb.w;
  }
#pragma unroll
  for (int off = 32; off; off >>= 1) {
    p0 += __shfl_down(p0, off); p1 += __shfl_down(p1, off);
    r0 += __shfl_down(r0, off); r1 += __shfl_down(r1, off);
  }
  if (!lane) { red[wv][0] = p0; red[wv][1] = p1; red[wv][2] = r0; red[wv][3] = r1; }
  __syncthreads();
  if (!t) {
    float P0 = red[0][0] + red[1][0] + red[2][0] + red[3][0];
    float P1 = red[0][1] + red[1][1] + red[2][1] + red[3][1];
    float R0 = red[0][2] + red[1][2] + red[2][2] + red[3][2];
    float R1 = red[0][3] + red[1][3] + red[2][3] + red[3][3];
    H3p[2 * n] = P0; H3p[2 * n + 1] = P1;
    es3[n] = P0 * a3s[0] + P1 * a3s[1];
    ed3[n] = P0 * a3d[0] + P1 * a3d[1];
    base[2 * n]     = R0 + skp[2 * n]     + b3[0];
    base[2 * n + 1] = R1 + skp[2 * n + 1] + b3[1];
  }
}

// ---------------- layer 3 softmax+aggregate (1 head, 2 ch) -> final logits ----------------
__global__ void k_l3agg(const int* __restrict__ rs, const int* __restrict__ esrc,
                        const float* __restrict__ H3p, const float* __restrict__ base,
                        const float* __restrict__ es3, const float* __restrict__ ed3,
                        float* __restrict__ out) {
  int n = blockIdx.x * 256 + threadIdx.x;
  if (n >= NN) return;
  int beg = rs[n], end = rs[n + 1];
  float edv = ed3[n];
  float den = 0.f, a0 = 0.f, a1 = 0.f;
  for (int j = beg; j < end; ++j) {
    int s = esrc[j];
    float e = es3[s] + edv;
    e = e > 0.f ? e : NEG * e;
    float exv = __expf(e);
    den += exv;
    a0 += exv * H3p[2 * s];
    a1 += exv * H3p[2 * s + 1];
  }
  float inv = 1.f / (den + 1e-16f);
  out[2 * n]     = base[2 * n]     + a0 * inv;
  out[2 * n + 1] = base[2 * n + 1] + a1 * inv;
}

extern "C" void kernel_launch(void* const* d_in, const int* in_sizes, int n_in,
                              void* d_out, int out_size, void* d_ws, size_t ws_size,
                              hipStream_t stream) {
  (void)in_sizes; (void)n_in; (void)out_size; (void)ws_size;
  const float* x    = (const float*)d_in[0];
  const int*   ei   = (const int*)d_in[1];
  const float* W1   = (const float*)d_in[2];
  const float* a1s  = (const float*)d_in[3];
  const float* a1d  = (const float*)d_in[4];
  const float* b1   = (const float*)d_in[5];
  const float* W2   = (const float*)d_in[6];
  const float* a2s  = (const float*)d_in[7];
  const float* a2d  = (const float*)d_in[8];
  const float* b2   = (const float*)d_in[9];
  const float* W3   = (const float*)d_in[10];
  const float* a3s  = (const float*)d_in[11];
  const float* a3d  = (const float*)d_in[12];
  const float* b3   = (const float*)d_in[13];
  const float* Wr1  = (const float*)d_in[14];
  const float* Wr2  = (const float*)d_in[15];
  const float* Wsk  = (const float*)d_in[16];
  float* out = (float*)d_out;

  // ---- workspace (~250 MB) ----
  char* w = (char*)d_ws;
  size_t off = 0;
  auto alloc = [&](size_t bytes) { void* p = w + off; off += (bytes + 255) & ~(size_t)255; return p; };
  int* cnt   = (int*)alloc((size_t)NN * 4);
  int* cur   = (int*)alloc((size_t)NN * 4);
  int* rs    = (int*)alloc((size_t)(NN + 1) * 4);
  int* bs    = (int*)alloc(256 * 4);
  int* esrc  = (int*)alloc((size_t)ETOT * 4);
  float* es  = (float*)alloc((size_t)MPAD * HEADS * 4);
  float* ed  = (float*)alloc((size_t)MPAD * HEADS * 4);
  u16* W1t   = (u16*)alloc((size_t)NP1 * KP1 * 2);
  u16* W2t   = (u16*)alloc((size_t)NP2 * DIM * 2);
  float* H3p = (float*)alloc((size_t)NN * 2 * 4);
  float* base= (float*)alloc((size_t)NN * 2 * 4);
  float* es3 = (float*)alloc((size_t)NN * 4);
  float* ed3 = (float*)alloc((size_t)NN * 4);
  float* skp = (float*)alloc((size_t)NN * 2 * 4);
  u16* bufB  = (u16*)alloc((size_t)MPAD * DIM * 2);    // h1bf (GEMM2 A)
  u16* bufA  = (u16*)alloc((size_t)MPAD * DIM2 * 2);   // H1p, later G2 (fused proj|resid)
  u16* H1p   = bufA;
  u16* G2    = bufA;
  u16* A1    = bufA + (size_t)MPAD * DIM;              // alias upper half of bufA (dead before G2)

  const int nb = (NN + 255) / 256;        // 196
  const int ge = (ETOT + 255) / 256;      // 977

  // fused prep (includes zeroing cnt/cur for the CSR build)
  k_prep<<<PR_Z, 256, 0, stream>>>(x, W1, a1s, a1d, W2, Wr1, a2s, a2d, Wsk,
                                   A1, W1t, W2t, skp, cnt, cur);

  // CSR build
  k_count<<<ge, 256, 0, stream>>>(ei, cnt);
  k_bsum <<<nb, 256, 0, stream>>>(cnt, bs);
  k_top  <<<1, 256, 0, stream>>>(bs, rs, nb);
  k_scan <<<nb, 256, 0, stream>>>(cnt, bs, rs);
  k_fill <<<ge, 256, 0, stream>>>(ei, rs, cur, esrc);

  // layer 1 (GEMM also emits es/ed via fused columns 800-815)
  k_gemm<<<dim3(NP1 / 128, MPAD / 128), 512, 0, stream>>>(A1, W1t, H1p, es, ed,
                                                          KP1 / 32, KP1, DIM, DIM + 16, DIM);
  k_agg1<<<NN, 256, 0, stream>>>(rs, esrc, H1p, es, ed, b1, bufB);

  // layer 2 (W2|Wres1 fused GEMM; es/ed via fused columns 1600-1615)
  k_gemm<<<dim3(NP2 / 128, MPAD / 128), 512, 0, stream>>>(bufB, W2t, G2, es, ed,
                                                          DIM / 32, DIM, DIM2, DIM2 + 16, DIM2);
  k_agg2f<<<NN, 256, 0, stream>>>(rs, esrc, G2, es, ed, b2, G2 + DIM,
                                  W3, Wr2, a3s, a3d, b3, skp, H3p, base, es3, ed3);

  // layer 3 softmax-aggregate
  k_l3agg<<<nb, 256, 0, stream>>>(rs, esrc, H3p, base, es3, ed3, out);
}